// Round 2
// baseline (1472.400 us; speedup 1.0000x reference)
//
#include <hip/hip_runtime.h>
#include <hip/hip_bf16.h>
#include <math.h>

// Problem constants (Qwen3Omni MoE block): B=2,S=2048 -> T=4096 tokens
#define TT 4096
#define HH 2048
#define EE 8
#define II 768
#define TWOI 1536

// ---------------------------------------------------------------------------
// Router: one wave (64 lanes) per token. logits = x @ gate_w (H x 8),
// softmax, top-2, normalized weights; scatters (token, weight) into per-expert
// buckets. counts[] doubles as the aux-loss selection-frequency numerator.
// ---------------------------------------------------------------------------
__global__ __launch_bounds__(256) void router_kernel(
    const float* __restrict__ x, const float* __restrict__ gw,
    float* __restrict__ logits_out,
    int* __restrict__ counts,
    int* __restrict__ bucket_tok, float* __restrict__ bucket_w)
{
    const int wave = threadIdx.x >> 6;
    const int lane = threadIdx.x & 63;
    const int t = blockIdx.x * 4 + wave;

    float acc[EE];
#pragma unroll
    for (int e = 0; e < EE; ++e) acc[e] = 0.f;

    // vectorized x loads: 16 B/lane, fully coalesced
    const float4* xr = (const float4*)(x + (size_t)t * HH);
    for (int i = lane; i < HH / 4; i += 64) {
        const float4 v = xr[i];
        const float* g = gw + (size_t)(i * 4) * EE;   // 4 consecutive gw rows
#pragma unroll
        for (int e = 0; e < EE; ++e)
            acc[e] += v.x * g[e] + v.y * g[e + EE]
                    + v.z * g[e + 2 * EE] + v.w * g[e + 3 * EE];
    }
    // butterfly reduce across the 64-lane wave
#pragma unroll
    for (int e = 0; e < EE; ++e) {
#pragma unroll
        for (int off = 32; off > 0; off >>= 1)
            acc[e] += __shfl_xor(acc[e], off, 64);
    }

    if (lane == 0) {
        float mx = acc[0];
#pragma unroll
        for (int e = 1; e < EE; ++e) mx = fmaxf(mx, acc[e]);
        float p[EE]; float s = 0.f;
#pragma unroll
        for (int e = 0; e < EE; ++e) { p[e] = expf(acc[e] - mx); s += p[e]; }
        const float inv = 1.f / s;
#pragma unroll
        for (int e = 0; e < EE; ++e) {
            p[e] *= inv;
            logits_out[(size_t)t * EE + e] = acc[e];
        }
        // top-2 (strict > keeps lowest index on ties, matching lax.top_k)
        int i0 = 0;
#pragma unroll
        for (int e = 1; e < EE; ++e) if (p[e] > p[i0]) i0 = e;
        int i1 = (i0 == 0) ? 1 : 0;
#pragma unroll
        for (int e = 0; e < EE; ++e) if (e != i0 && p[e] > p[i1]) i1 = e;
        const float denom = 1.f / (p[i0] + p[i1]);
        const float w0 = p[i0] * denom, w1 = p[i1] * denom;
        int pos0 = atomicAdd(&counts[i0], 1);
        bucket_tok[i0 * TT + pos0] = t; bucket_w[i0 * TT + pos0] = w0;
        int pos1 = atomicAdd(&counts[i1], 1);
        bucket_tok[i1 * TT + pos1] = t; bucket_w[i1 * TT + pos1] = w1;
    }
}

// ---------------------------------------------------------------------------
// Finalize: recompute softmax-prob sums from logits (deterministic, no global
// atomics), then bucket offsets (exclusive scan over E=8) + aux loss scalar.
// One block, 256 threads.
// ---------------------------------------------------------------------------
__global__ __launch_bounds__(256) void finalize_router(
    const float* __restrict__ logits, const int* __restrict__ counts,
    int* __restrict__ offsets, float* __restrict__ aux_out)
{
    __shared__ float sums[EE];
    if (threadIdx.x < EE) sums[threadIdx.x] = 0.f;
    __syncthreads();

    float loc[EE];
#pragma unroll
    for (int e = 0; e < EE; ++e) loc[e] = 0.f;

    for (int t = threadIdx.x; t < TT; t += 256) {
        const float* lr = logits + (size_t)t * EE;
        float l[EE];
        float mx = -1e30f;
#pragma unroll
        for (int e = 0; e < EE; ++e) { l[e] = lr[e]; mx = fmaxf(mx, l[e]); }
        float s = 0.f, p[EE];
#pragma unroll
        for (int e = 0; e < EE; ++e) { p[e] = expf(l[e] - mx); s += p[e]; }
        const float inv = 1.f / s;
#pragma unroll
        for (int e = 0; e < EE; ++e) loc[e] += p[e] * inv;
    }
#pragma unroll
    for (int e = 0; e < EE; ++e) atomicAdd(&sums[e], loc[e]);  // LDS atomics
    __syncthreads();

    if (threadIdx.x == 0) {
        int o = 0; float aux = 0.f;
        for (int e = 0; e < EE; ++e) {
            offsets[e] = o; o += counts[e];
            aux += (sums[e] / (float)TT) * ((float)counts[e] / (float)TT);
        }
        aux_out[0] = aux * (float)EE * 0.001f;
    }
}

// ---------------------------------------------------------------------------
// Stage 1: per-expert GEMM  gu[row][j] = sum_h x[tok[row]][h] * Wgu[e][j][h]
// gate half (n0+tx*4..) and up half (768+n0+tx*4..) computed together, fused
// SiLU(gate)*up -> inter[offsets[e]+row][...]. Tile 128 rows x 64 pair-cols,
// BK=8, 256 threads, dual 8x4 microtile. All LDS reads are broadcast or
// 2-way (free).
// ---------------------------------------------------------------------------
__global__ __launch_bounds__(256) void moe_gateup(
    const float* __restrict__ x, const float* __restrict__ Wgu,
    const int* __restrict__ counts, const int* __restrict__ offsets,
    const int* __restrict__ bucket_tok, float* __restrict__ inter)
{
    const int e = blockIdx.z;
    const int cnt = counts[e];
    const int m0 = blockIdx.y * 128;
    if (m0 >= cnt) return;
    const int n0 = blockIdx.x * 64;       // pair-column base, [0,768)
    const int base = offsets[e];

    __shared__ float As[8][128];
    __shared__ float Bs[8][128];          // [k][0..63]=gate rows, [64..127]=up rows

    const int tid = threadIdx.x;
    const int ar = tid >> 1;              // 0..127
    const int ak = (tid & 1) * 4;         // 0 or 4
    const int arow = m0 + ar;
    const int tok = (arow < cnt) ? bucket_tok[e * TT + arow] : 0;
    const float* aptr = x + (size_t)tok * HH + ak;

    const int br = ar;
    const int bj = (br < 64) ? (n0 + br) : (II + n0 + (br - 64));
    const float* bptr = Wgu + ((size_t)e * TWOI + bj) * HH + ak;

    const int tx = tid & 15, ty = tid >> 4;

    float acc_g[8][4], acc_u[8][4];
#pragma unroll
    for (int m = 0; m < 8; ++m)
#pragma unroll
        for (int n = 0; n < 4; ++n) { acc_g[m][n] = 0.f; acc_u[m][n] = 0.f; }

    float4 av = *(const float4*)(aptr);
    float4 bv = *(const float4*)(bptr);

    for (int k0 = 0; k0 < HH; k0 += 8) {
        __syncthreads();
        As[ak + 0][ar] = av.x; As[ak + 1][ar] = av.y;
        As[ak + 2][ar] = av.z; As[ak + 3][ar] = av.w;
        Bs[ak + 0][br] = bv.x; Bs[ak + 1][br] = bv.y;
        Bs[ak + 2][br] = bv.z; Bs[ak + 3][br] = bv.w;
        __syncthreads();
        if (k0 + 8 < HH) {                 // prefetch next K-slab
            av = *(const float4*)(aptr + k0 + 8);
            bv = *(const float4*)(bptr + k0 + 8);
        }
#pragma unroll
        for (int k = 0; k < 8; ++k) {
            float4 a0 = *(const float4*)&As[k][ty * 8];
            float4 a1 = *(const float4*)&As[k][ty * 8 + 4];
            float4 bg = *(const float4*)&Bs[k][tx * 4];
            float4 bu = *(const float4*)&Bs[k][64 + tx * 4];
            float am[8] = {a0.x, a0.y, a0.z, a0.w, a1.x, a1.y, a1.z, a1.w};
            float bgm[4] = {bg.x, bg.y, bg.z, bg.w};
            float bum[4] = {bu.x, bu.y, bu.z, bu.w};
#pragma unroll
            for (int m = 0; m < 8; ++m)
#pragma unroll
                for (int n = 0; n < 4; ++n) {
                    acc_g[m][n] = fmaf(am[m], bgm[n], acc_g[m][n]);
                    acc_u[m][n] = fmaf(am[m], bum[n], acc_u[m][n]);
                }
        }
    }

#pragma unroll
    for (int m = 0; m < 8; ++m) {
        const int r = m0 + ty * 8 + m;
        if (r < cnt) {
            float* dst = inter + (size_t)(base + r) * II + n0 + tx * 4;
#pragma unroll
            for (int n = 0; n < 4; ++n) {
                const float g = acc_g[m][n];
                const float s = g / (1.f + expf(-g));   // SiLU
                dst[n] = s * acc_u[m][n];
            }
        }
    }
}

// ---------------------------------------------------------------------------
// Stage 2: per-expert GEMM  out[tok][h] += w * sum_i inter[row][i]*Wd[e][h][i]
// Tile 128 rows x 128 h, BK=8, 256 threads, 8x(4+4) microtile (dual float4
// fragments at tx*4 and 64+tx*4 -> 2-way LDS access, free; tx*8 was 4-way).
// atomicAdd epilogue: exactly 2 commutative contributions/element.
// ---------------------------------------------------------------------------
__global__ __launch_bounds__(256) void moe_down(
    const float* __restrict__ inter, const float* __restrict__ Wd,
    const int* __restrict__ counts, const int* __restrict__ offsets,
    const int* __restrict__ bucket_tok, const float* __restrict__ bucket_w,
    float* __restrict__ out)
{
    const int e = blockIdx.z;
    const int cnt = counts[e];
    const int m0 = blockIdx.y * 128;
    if (m0 >= cnt) return;
    const int n0 = blockIdx.x * 128;
    const int base = offsets[e];

    __shared__ float As[8][128];
    __shared__ float Bs[8][128];

    const int tid = threadIdx.x;
    const int ar = tid >> 1;
    const int ak = (tid & 1) * 4;
    const int arow = m0 + ar;
    const int asafe = (arow < cnt) ? arow : 0;
    const float* aptr = inter + (size_t)(base + asafe) * II + ak;
    const float* bptr = Wd + ((size_t)e * HH + n0 + ar) * II + ak;

    const int tx = tid & 15, ty = tid >> 4;

    float acc0[8][4], acc1[8][4];
#pragma unroll
    for (int m = 0; m < 8; ++m)
#pragma unroll
        for (int n = 0; n < 4; ++n) { acc0[m][n] = 0.f; acc1[m][n] = 0.f; }

    float4 av = *(const float4*)(aptr);
    float4 bv = *(const float4*)(bptr);

    for (int k0 = 0; k0 < II; k0 += 8) {
        __syncthreads();
        As[ak + 0][ar] = av.x; As[ak + 1][ar] = av.y;
        As[ak + 2][ar] = av.z; As[ak + 3][ar] = av.w;
        Bs[ak + 0][ar] = bv.x; Bs[ak + 1][ar] = bv.y;
        Bs[ak + 2][ar] = bv.z; Bs[ak + 3][ar] = bv.w;
        __syncthreads();
        if (k0 + 8 < II) {
            av = *(const float4*)(aptr + k0 + 8);
            bv = *(const float4*)(bptr + k0 + 8);
        }
#pragma unroll
        for (int k = 0; k < 8; ++k) {
            float4 a0 = *(const float4*)&As[k][ty * 8];
            float4 a1 = *(const float4*)&As[k][ty * 8 + 4];
            float4 b0 = *(const float4*)&Bs[k][tx * 4];
            float4 b1 = *(const float4*)&Bs[k][64 + tx * 4];
            float am[8] = {a0.x, a0.y, a0.z, a0.w, a1.x, a1.y, a1.z, a1.w};
            float b0m[4] = {b0.x, b0.y, b0.z, b0.w};
            float b1m[4] = {b1.x, b1.y, b1.z, b1.w};
#pragma unroll
            for (int m = 0; m < 8; ++m)
#pragma unroll
                for (int n = 0; n < 4; ++n) {
                    acc0[m][n] = fmaf(am[m], b0m[n], acc0[m][n]);
                    acc1[m][n] = fmaf(am[m], b1m[n], acc1[m][n]);
                }
        }
    }

#pragma unroll
    for (int m = 0; m < 8; ++m) {
        const int r = m0 + ty * 8 + m;
        if (r < cnt) {
            const int tok = bucket_tok[e * TT + r];
            const float w = bucket_w[e * TT + r];
            float* dst0 = out + (size_t)tok * HH + n0 + tx * 4;
            float* dst1 = dst0 + 64;
#pragma unroll
            for (int n = 0; n < 4; ++n) {
                atomicAdd(&dst0[n], w * acc0[m][n]);
                atomicAdd(&dst1[n], w * acc1[m][n]);
            }
        }
    }
}

// ---------------------------------------------------------------------------
// Launch
// ---------------------------------------------------------------------------
extern "C" void kernel_launch(void* const* d_in, const int* in_sizes, int n_in,
                              void* d_out, int out_size, void* d_ws, size_t ws_size,
                              hipStream_t stream)
{
    const float* x   = (const float*)d_in[0];   // (T, H)
    const float* gw  = (const float*)d_in[1];   // (H, E)
    const float* wgu = (const float*)d_in[2];   // (E, 2I, H)
    const float* wd  = (const float*)d_in[3];   // (E, H, I)

    float* out_final  = (float*)d_out;                    // (T, H)
    float* out_logits = out_final + (size_t)TT * HH;      // (T, E)
    float* out_aux    = out_logits + (size_t)TT * EE;     // scalar

    // workspace layout (4B units):
    //   [0..8)   counts, [8..16) offsets
    //   [64 ..)              bucket_tok  E*T ints
    //   [64+E*T ..)          bucket_w    E*T floats
    //   [64+2*E*T ..)        inter       8192*768 floats (~25 MB)
    int*   counts     = (int*)d_ws;
    int*   offsets    = counts + 8;
    int*   bucket_tok = (int*)d_ws + 64;
    float* bucket_w   = (float*)d_ws + 64 + EE * TT;
    float* inter      = (float*)d_ws + 64 + 2 * EE * TT;

    hipMemsetAsync(d_ws, 0, 256, stream);                              // counts
    hipMemsetAsync(d_out, 0, sizeof(float) * (size_t)TT * HH, stream); // accum target

    router_kernel<<<TT / 4, 256, 0, stream>>>(x, gw, out_logits, counts,
                                              bucket_tok, bucket_w);
    finalize_router<<<1, 256, 0, stream>>>(out_logits, counts, offsets, out_aux);
    moe_gateup<<<dim3(II / 64, TT / 128, EE), 256, 0, stream>>>(
        x, wgu, counts, offsets, bucket_tok, inter);
    moe_down<<<dim3(HH / 128, TT / 128, EE), 256, 0, stream>>>(
        inter, wd, counts, offsets, bucket_tok, bucket_w, out_final);
}

// Round 4
// 674.560 us; speedup vs baseline: 2.1828x; 2.1828x over previous
//
#include <hip/hip_runtime.h>
#include <hip/hip_bf16.h>
#include <math.h>

// Problem constants: B=2,S=2048 -> T=4096 tokens, H=2048, E=8, I=768, top-2
#define TT 4096
#define HH 2048
#define EE 8
#define II 768
#define TWOI 1536

typedef __attribute__((ext_vector_type(8))) short bf16v8;   // 8 bf16 = 4 VGPR
typedef __attribute__((ext_vector_type(4))) float f32x4;

// round-to-nearest-even fp32 -> bf16 (bits)
static __device__ __forceinline__ unsigned short f2bf(float f) {
    unsigned int u = __float_as_uint(f);
    unsigned int r = (u + 0x7fffu + ((u >> 16) & 1u)) >> 16;
    return (unsigned short)r;
}
static __device__ __forceinline__ float bf2f(unsigned short b) {
    return __uint_as_float(((unsigned int)b) << 16);
}
// 8 floats -> hi uint4 (8 bf16) and lo uint4 (residual 8 bf16)
static __device__ __forceinline__ void cvt8(const float4 v0, const float4 v1,
                                            uint4& hi, uint4& lo) {
    float f[8] = {v0.x, v0.y, v0.z, v0.w, v1.x, v1.y, v1.z, v1.w};
    unsigned short h[8], l[8];
#pragma unroll
    for (int i = 0; i < 8; ++i) {
        h[i] = f2bf(f[i]);
        l[i] = f2bf(f[i] - bf2f(h[i]));
    }
    hi = make_uint4((unsigned)h[0] | ((unsigned)h[1] << 16),
                    (unsigned)h[2] | ((unsigned)h[3] << 16),
                    (unsigned)h[4] | ((unsigned)h[5] << 16),
                    (unsigned)h[6] | ((unsigned)h[7] << 16));
    lo = make_uint4((unsigned)l[0] | ((unsigned)l[1] << 16),
                    (unsigned)l[2] | ((unsigned)l[3] << 16),
                    (unsigned)l[4] | ((unsigned)l[5] << 16),
                    (unsigned)l[6] | ((unsigned)l[7] << 16));
}

// ---------------------------------------------------------------------------
// Router: one wave per token (unchanged from R2 — passed validation).
// ---------------------------------------------------------------------------
__global__ __launch_bounds__(256) void router_kernel(
    const float* __restrict__ x, const float* __restrict__ gw,
    float* __restrict__ logits_out, int* __restrict__ counts,
    int* __restrict__ bucket_tok, float* __restrict__ bucket_w)
{
    const int wave = threadIdx.x >> 6;
    const int lane = threadIdx.x & 63;
    const int t = blockIdx.x * 4 + wave;

    float acc[EE];
#pragma unroll
    for (int e = 0; e < EE; ++e) acc[e] = 0.f;

    const float4* xr = (const float4*)(x + (size_t)t * HH);
    for (int i = lane; i < HH / 4; i += 64) {
        const float4 v = xr[i];
        const float* g = gw + (size_t)(i * 4) * EE;
#pragma unroll
        for (int e = 0; e < EE; ++e)
            acc[e] += v.x * g[e] + v.y * g[e + EE]
                    + v.z * g[e + 2 * EE] + v.w * g[e + 3 * EE];
    }
#pragma unroll
    for (int e = 0; e < EE; ++e) {
#pragma unroll
        for (int off = 32; off > 0; off >>= 1)
            acc[e] += __shfl_xor(acc[e], off, 64);
    }

    if (lane == 0) {
        float mx = acc[0];
#pragma unroll
        for (int e = 1; e < EE; ++e) mx = fmaxf(mx, acc[e]);
        float p[EE]; float s = 0.f;
#pragma unroll
        for (int e = 0; e < EE; ++e) { p[e] = expf(acc[e] - mx); s += p[e]; }
        const float inv = 1.f / s;
#pragma unroll
        for (int e = 0; e < EE; ++e) {
            p[e] *= inv;
            logits_out[(size_t)t * EE + e] = acc[e];
        }
        int i0 = 0;
#pragma unroll
        for (int e = 1; e < EE; ++e) if (p[e] > p[i0]) i0 = e;
        int i1 = (i0 == 0) ? 1 : 0;
#pragma unroll
        for (int e = 0; e < EE; ++e) if (e != i0 && p[e] > p[i1]) i1 = e;
        const float denom = 1.f / (p[i0] + p[i1]);
        const float w0 = p[i0] * denom, w1 = p[i1] * denom;
        int pos0 = atomicAdd(&counts[i0], 1);
        bucket_tok[i0 * TT + pos0] = t; bucket_w[i0 * TT + pos0] = w0;
        int pos1 = atomicAdd(&counts[i1], 1);
        bucket_tok[i1 * TT + pos1] = t; bucket_w[i1 * TT + pos1] = w1;
    }
}

__global__ __launch_bounds__(256) void finalize_router(
    const float* __restrict__ logits, const int* __restrict__ counts,
    int* __restrict__ offsets, float* __restrict__ aux_out)
{
    __shared__ float sums[EE];
    if (threadIdx.x < EE) sums[threadIdx.x] = 0.f;
    __syncthreads();
    float loc[EE];
#pragma unroll
    for (int e = 0; e < EE; ++e) loc[e] = 0.f;
    for (int t = threadIdx.x; t < TT; t += 256) {
        const float* lr = logits + (size_t)t * EE;
        float l[EE]; float mx = -1e30f;
#pragma unroll
        for (int e = 0; e < EE; ++e) { l[e] = lr[e]; mx = fmaxf(mx, l[e]); }
        float s = 0.f, p[EE];
#pragma unroll
        for (int e = 0; e < EE; ++e) { p[e] = expf(l[e] - mx); s += p[e]; }
        const float inv = 1.f / s;
#pragma unroll
        for (int e = 0; e < EE; ++e) loc[e] += p[e] * inv;
    }
#pragma unroll
    for (int e = 0; e < EE; ++e) atomicAdd(&sums[e], loc[e]);
    __syncthreads();
    if (threadIdx.x == 0) {
        int o = 0; float aux = 0.f;
        for (int e = 0; e < EE; ++e) {
            offsets[e] = o; o += counts[e];
            aux += (sums[e] / (float)TT) * ((float)counts[e] / (float)TT);
        }
        aux_out[0] = aux * (float)EE * 0.001f;
    }
}

// ---------------------------------------------------------------------------
// bf16x3 MFMA GEMM stage 1 (gate_up + SiLU fuse).
// Tile 128 rows x 64 pair-cols (= 128 phys cols: 2x{32 gate + 32 up}).
// BK=32 fp32, split hi/lo bf16 in LDS (XOR-swizzled units, involution on
// both write and read sides), 4 waves 2x2, per wave 4x4 fragments of
// mfma_f32_16x16x32_bf16, 3 terms each (hi*hi + hi*lo + lo*hi).
// LDS 32 KB. Grid 1-D, chunk-swizzled: expert e -> XCD e.
// ---------------------------------------------------------------------------
#define AHI 0
#define ALO 8192
#define BHI 16384
#define BLO 24576

__global__ __launch_bounds__(256, 2) void moe_gateup(
    const float* __restrict__ x, const float* __restrict__ Wgu,
    const int* __restrict__ counts, const int* __restrict__ offsets,
    const int* __restrict__ bucket_tok, float* __restrict__ inter)
{
    // bijective chunk swizzle: 3072 blocks -> 8 chunks of 384 (one expert/XCD)
    const int bid = blockIdx.x;
    const int e = bid & 7;
    const int rem = bid >> 3;           // 0..383, n fastest
    const int mb = rem / 12, nb = rem % 12;

    const int cnt = counts[e];
    const int m0 = mb * 128;
    if (m0 >= cnt) return;
    const int n0 = nb * 64;             // pair-col base
    const int base = offsets[e];

    __shared__ unsigned char smem[32768];

    const int tid = threadIdx.x;
    const int lane = tid & 63;
    const int wid = tid >> 6;
    const int wm = wid >> 1, wn = wid & 1;

    // staging assignment: thread -> (row, k-half)
    const int srow = tid >> 1;          // 0..127
    const int sseg = tid & 1;           // k offset 16*sseg
    const int arow = m0 + srow;
    const int atok = (arow < cnt) ? bucket_tok[e * TT + arow] : 0;
    const float* ag = x + (size_t)atok * HH + sseg * 16;
    const int bblk = srow >> 5, bc = srow & 31;
    const int bj = ((bblk & 1) ? II : 0) + n0 + ((bblk >> 1) << 5) + bc;
    const float* bg = Wgu + ((size_t)e * TWOI + bj) * HH + sseg * 16;
    // swizzled LDS write offsets (two 16B units per thread per tile)
    const int au0 = srow * 64 + (((sseg << 1) | 0) ^ (srow & 3)) * 16;
    const int au1 = srow * 64 + (((sseg << 1) | 1) ^ (srow & 3)) * 16;

    // fragment read offsets (hoisted)
    int aoff[4], boff[4];
#pragma unroll
    for (int i = 0; i < 4; ++i) {
        int ra = wm * 64 + i * 16 + (lane & 15);
        aoff[i] = ra * 64 + (((lane >> 4) ^ (ra & 3)) * 16);
        int rb = wn * 64 + i * 16 + (lane & 15);
        boff[i] = rb * 64 + (((lane >> 4) ^ (rb & 3)) * 16);
    }

    f32x4 acc[4][4];
#pragma unroll
    for (int i = 0; i < 4; ++i)
#pragma unroll
        for (int j = 0; j < 4; ++j) acc[i][j] = f32x4{0.f, 0.f, 0.f, 0.f};

    float4 pa0 = *(const float4*)(ag + 0), pa1 = *(const float4*)(ag + 4);
    float4 pa2 = *(const float4*)(ag + 8), pa3 = *(const float4*)(ag + 12);
    float4 pb0 = *(const float4*)(bg + 0), pb1 = *(const float4*)(bg + 4);
    float4 pb2 = *(const float4*)(bg + 8), pb3 = *(const float4*)(bg + 12);

    const int NS = HH / 32;             // 64 K-steps
    for (int s = 0; s < NS; ++s) {
        __syncthreads();
        uint4 hi, lo;
        cvt8(pa0, pa1, hi, lo);
        *(uint4*)(smem + AHI + au0) = hi; *(uint4*)(smem + ALO + au0) = lo;
        cvt8(pa2, pa3, hi, lo);
        *(uint4*)(smem + AHI + au1) = hi; *(uint4*)(smem + ALO + au1) = lo;
        cvt8(pb0, pb1, hi, lo);
        *(uint4*)(smem + BHI + au0) = hi; *(uint4*)(smem + BLO + au0) = lo;
        cvt8(pb2, pb3, hi, lo);
        *(uint4*)(smem + BHI + au1) = hi; *(uint4*)(smem + BLO + au1) = lo;
        __syncthreads();
        if (s + 1 < NS) {               // prefetch next K-slab (hides under MFMA)
            const int k0 = (s + 1) * 32;
            pa0 = *(const float4*)(ag + k0); pa1 = *(const float4*)(ag + k0 + 4);
            pa2 = *(const float4*)(ag + k0 + 8); pa3 = *(const float4*)(ag + k0 + 12);
            pb0 = *(const float4*)(bg + k0); pb1 = *(const float4*)(bg + k0 + 4);
            pb2 = *(const float4*)(bg + k0 + 8); pb3 = *(const float4*)(bg + k0 + 12);
        }
        bf16v8 ah[4], al[4], bh[4], bl[4];
#pragma unroll
        for (int i = 0; i < 4; ++i) {
            ah[i] = *(const bf16v8*)(smem + AHI + aoff[i]);
            al[i] = *(const bf16v8*)(smem + ALO + aoff[i]);
            bh[i] = *(const bf16v8*)(smem + BHI + boff[i]);
            bl[i] = *(const bf16v8*)(smem + BLO + boff[i]);
        }
#pragma unroll
        for (int i = 0; i < 4; ++i)
#pragma unroll
            for (int j = 0; j < 4; ++j) {
                acc[i][j] = __builtin_amdgcn_mfma_f32_16x16x32_bf16(ah[i], bh[j], acc[i][j], 0, 0, 0);
                acc[i][j] = __builtin_amdgcn_mfma_f32_16x16x32_bf16(ah[i], bl[j], acc[i][j], 0, 0, 0);
                acc[i][j] = __builtin_amdgcn_mfma_f32_16x16x32_bf16(al[i], bh[j], acc[i][j], 0, 0, 0);
            }
    }

    // epilogue: SiLU(gate)*up; fragments j=0,1 are gate, j=2,3 the matching up
#pragma unroll
    for (int mi = 0; mi < 4; ++mi)
#pragma unroll
        for (int np = 0; np < 2; ++np) {
            const f32x4 g = acc[mi][np], u = acc[mi][np + 2];
            const int colp = n0 + wn * 32 + np * 16 + (lane & 15);
#pragma unroll
            for (int j = 0; j < 4; ++j) {
                const int r = m0 + wm * 64 + mi * 16 + ((lane >> 4) << 2) + j;
                if (r < cnt) {
                    const float gg = g[j];
                    const float sv = gg / (1.f + expf(-gg));
                    inter[(size_t)(base + r) * II + colp] = sv * u[j];
                }
            }
        }
}

// ---------------------------------------------------------------------------
// bf16x3 MFMA GEMM stage 2 (down proj, weighted atomic scatter).
// Tile 128 rows x 128 h-cols, K=II=768, BK=32. Same structure as stage 1.
// ---------------------------------------------------------------------------
__global__ __launch_bounds__(256, 2) void moe_down(
    const float* __restrict__ inter, const float* __restrict__ Wd,
    const int* __restrict__ counts, const int* __restrict__ offsets,
    const int* __restrict__ bucket_tok, const float* __restrict__ bucket_w,
    float* __restrict__ out)
{
    // 4096 blocks -> 8 chunks of 512 (one expert/XCD), n fastest
    const int bid = blockIdx.x;
    const int e = bid & 7;
    const int rem = bid >> 3;           // 0..511
    const int mb = rem >> 4, nb = rem & 15;

    const int cnt = counts[e];
    const int m0 = mb * 128;
    if (m0 >= cnt) return;
    const int n0 = nb * 128;
    const int base = offsets[e];

    __shared__ unsigned char smem[32768];

    const int tid = threadIdx.x;
    const int lane = tid & 63;
    const int wid = tid >> 6;
    const int wm = wid >> 1, wn = wid & 1;

    const int srow = tid >> 1;
    const int sseg = tid & 1;
    const int arow = m0 + srow;
    const int asafe = (arow < cnt) ? arow : 0;
    const float* ag = inter + (size_t)(base + asafe) * II + sseg * 16;
    const float* bg = Wd + ((size_t)e * HH + n0 + srow) * II + sseg * 16;
    const int au0 = srow * 64 + (((sseg << 1) | 0) ^ (srow & 3)) * 16;
    const int au1 = srow * 64 + (((sseg << 1) | 1) ^ (srow & 3)) * 16;

    int aoff[4], boff[4];
#pragma unroll
    for (int i = 0; i < 4; ++i) {
        int ra = wm * 64 + i * 16 + (lane & 15);
        aoff[i] = ra * 64 + (((lane >> 4) ^ (ra & 3)) * 16);
        int rb = wn * 64 + i * 16 + (lane & 15);
        boff[i] = rb * 64 + (((lane >> 4) ^ (rb & 3)) * 16);
    }

    f32x4 acc[4][4];
#pragma unroll
    for (int i = 0; i < 4; ++i)
#pragma unroll
        for (int j = 0; j < 4; ++j) acc[i][j] = f32x4{0.f, 0.f, 0.f, 0.f};

    float4 pa0 = *(const float4*)(ag + 0), pa1 = *(const float4*)(ag + 4);
    float4 pa2 = *(const float4*)(ag + 8), pa3 = *(const float4*)(ag + 12);
    float4 pb0 = *(const float4*)(bg + 0), pb1 = *(const float4*)(bg + 4);
    float4 pb2 = *(const float4*)(bg + 8), pb3 = *(const float4*)(bg + 12);

    const int NS = II / 32;             // 24 K-steps
    for (int s = 0; s < NS; ++s) {
        __syncthreads();
        uint4 hi, lo;
        cvt8(pa0, pa1, hi, lo);
        *(uint4*)(smem + AHI + au0) = hi; *(uint4*)(smem + ALO + au0) = lo;
        cvt8(pa2, pa3, hi, lo);
        *(uint4*)(smem + AHI + au1) = hi; *(uint4*)(smem + ALO + au1) = lo;
        cvt8(pb0, pb1, hi, lo);
        *(uint4*)(smem + BHI + au0) = hi; *(uint4*)(smem + BLO + au0) = lo;
        cvt8(pb2, pb3, hi, lo);
        *(uint4*)(smem + BHI + au1) = hi; *(uint4*)(smem + BLO + au1) = lo;
        __syncthreads();
        if (s + 1 < NS) {
            const int k0 = (s + 1) * 32;
            pa0 = *(const float4*)(ag + k0); pa1 = *(const float4*)(ag + k0 + 4);
            pa2 = *(const float4*)(ag + k0 + 8); pa3 = *(const float4*)(ag + k0 + 12);
            pb0 = *(const float4*)(bg + k0); pb1 = *(const float4*)(bg + k0 + 4);
            pb2 = *(const float4*)(bg + k0 + 8); pb3 = *(const float4*)(bg + k0 + 12);
        }
        bf16v8 ah[4], al[4], bh[4], bl[4];
#pragma unroll
        for (int i = 0; i < 4; ++i) {
            ah[i] = *(const bf16v8*)(smem + AHI + aoff[i]);
            al[i] = *(const bf16v8*)(smem + ALO + aoff[i]);
            bh[i] = *(const bf16v8*)(smem + BHI + boff[i]);
            bl[i] = *(const bf16v8*)(smem + BLO + boff[i]);
        }
#pragma unroll
        for (int i = 0; i < 4; ++i)
#pragma unroll
            for (int j = 0; j < 4; ++j) {
                acc[i][j] = __builtin_amdgcn_mfma_f32_16x16x32_bf16(ah[i], bh[j], acc[i][j], 0, 0, 0);
                acc[i][j] = __builtin_amdgcn_mfma_f32_16x16x32_bf16(ah[i], bl[j], acc[i][j], 0, 0, 0);
                acc[i][j] = __builtin_amdgcn_mfma_f32_16x16x32_bf16(al[i], bh[j], acc[i][j], 0, 0, 0);
            }
    }

#pragma unroll
    for (int mi = 0; mi < 4; ++mi) {
        int rtok[4]; float rw[4]; int rok[4];
#pragma unroll
        for (int j = 0; j < 4; ++j) {
            const int r = m0 + wm * 64 + mi * 16 + ((lane >> 4) << 2) + j;
            rok[j] = (r < cnt);
            rtok[j] = rok[j] ? bucket_tok[e * TT + r] : 0;
            rw[j] = rok[j] ? bucket_w[e * TT + r] : 0.f;
        }
#pragma unroll
        for (int ni = 0; ni < 4; ++ni) {
            const int col = n0 + wn * 64 + ni * 16 + (lane & 15);
#pragma unroll
            for (int j = 0; j < 4; ++j)
                if (rok[j])
                    atomicAdd(out + (size_t)rtok[j] * HH + col, rw[j] * acc[mi][ni][j]);
        }
    }
}

// ---------------------------------------------------------------------------
// Launch
// ---------------------------------------------------------------------------
extern "C" void kernel_launch(void* const* d_in, const int* in_sizes, int n_in,
                              void* d_out, int out_size, void* d_ws, size_t ws_size,
                              hipStream_t stream)
{
    const float* x   = (const float*)d_in[0];
    const float* gw  = (const float*)d_in[1];
    const float* wgu = (const float*)d_in[2];
    const float* wd  = (const float*)d_in[3];

    float* out_final  = (float*)d_out;
    float* out_logits = out_final + (size_t)TT * HH;
    float* out_aux    = out_logits + (size_t)TT * EE;

    int*   counts     = (int*)d_ws;
    int*   offsets    = counts + 8;
    int*   bucket_tok = (int*)d_ws + 64;
    float* bucket_w   = (float*)d_ws + 64 + EE * TT;
    float* inter      = (float*)d_ws + 64 + 2 * EE * TT;

    hipMemsetAsync(d_ws, 0, 256, stream);
    hipMemsetAsync(d_out, 0, sizeof(float) * (size_t)TT * HH, stream);

    router_kernel<<<TT / 4, 256, 0, stream>>>(x, gw, out_logits, counts,
                                              bucket_tok, bucket_w);
    finalize_router<<<1, 256, 0, stream>>>(out_logits, counts, offsets, out_aux);
    moe_gateup<<<12 * 32 * EE, 256, 0, stream>>>(x, wgu, counts, offsets,
                                                 bucket_tok, inter);
    moe_down<<<16 * 32 * EE, 256, 0, stream>>>(inter, wd, counts, offsets,
                                               bucket_tok, bucket_w, out_final);
}